// Round 5
// baseline (301.776 us; speedup 1.0000x reference)
//
#include <hip/hip_runtime.h>

// Problem constants (fixed by reference setup)
#define B_ 4
#define N_ 96
#define T_ 512
#define G_ 8
#define NIMG (B_*12*T_)   // 24576 images

typedef _Float16 half8 __attribute__((ext_vector_type(8)));
typedef _Float16 half2t __attribute__((ext_vector_type(2)));
typedef float floatx4 __attribute__((ext_vector_type(4)));
typedef float floatx2 __attribute__((ext_vector_type(2)));

// ---------- math helpers ----------
__device__ __forceinline__ float softplusf(float x) {
    return (x > 15.0f) ? x : __logf(1.0f + __expf(x));
}
// branchless softplus (sigma path: args within +-4)
__device__ __forceinline__ float softplus_small(float x) {
    return __logf(1.0f + __expf(x));
}
__device__ __forceinline__ float fast_tanhf(float x) {
    float ax = fabsf(x);
    float e  = __expf(-2.0f * ax);
    float r  = (1.0f - e) * __builtin_amdgcn_rcpf(1.0f + e);
    return copysignf(r, x);
}
// odd Pade(5,4) tanh, |x| <= 1: abs err ~1e-5, no exp (r3/r4-verified)
__device__ __forceinline__ float tanh_pade(float x) {
    float x2 = x * x;
    float num = fmaf(x2, x2 + 105.0f, 945.0f);          // x^4+105x^2+945
    float den = fmaf(x2, fmaf(x2, 15.0f, 420.0f), 945.0f);
    return x * num * __builtin_amdgcn_rcpf(den);
}
// GELU with 3-term Abramowitz-Stegun erf (abs err 2.5e-5)
__device__ __forceinline__ float geluf(float x) {
    float z  = 0.70710678118654752f * x;
    float az = fabsf(z);
    float t  = __builtin_amdgcn_rcpf(fmaf(0.47047f, az, 1.0f));
    float poly = t * fmaf(t, fmaf(t, 0.7478556f, -0.0958798f), 0.3480242f);
    float e  = __expf(-az * az);
    float er = fmaf(-poly, e, 1.0f);     // erf(|z|)
    er = copysignf(er, z);
    return 0.5f * x * (1.0f + er);
}
// force a block-uniform float into an SGPR
__device__ __forceinline__ float rfl(float x) {
    return __int_as_float(__builtin_amdgcn_readfirstlane(__float_as_int(x)));
}

// ---------- K1: splat ----------
// grid 1536 = (b, k, 16 t-tiles of 32, 2 n-halves). block (64,4):
//   wave = 32t x 2ch (r0-proven lane layout, n wave-uniform);
//   threadIdx.y = n-chunk of 12 (block covers 48 n = one half).
// Rationale (r0-r4 ledger): splat wall is dominated by load-imbalance tail
// (hem-pass-rate varies per (k,n,t); occupancy 24% vs 37.5% grid cap).
// Halving per-block work + 6 blocks/CU queued vs 3 resident -> backfill.
// Inner loop = r0 body verbatim (r2's divergent-n and r3's in-chain LDS
// reads both regressed; SH stays inline from global).
// Each block writes a PARTIAL 32x128 f16 image; cnn sums the two halves.
__global__ __launch_bounds__(256, 3) void splat_kernel(
    const float* __restrict__ mu,  const float* __restrict__ sg0,
    const float* __restrict__ sgv, const float* __restrict__ amp,
    const float* __restrict__ shb, const float* __restrict__ shv,
    const float* __restrict__ p0,  const float* __restrict__ pv,
    const float* __restrict__ tau_raw, const float* __restrict__ da_raw,
    const float* __restrict__ ra, const float* __restrict__ la,
    const float* __restrict__ ll, const float* __restrict__ chest,
    const float* __restrict__ w1, const float* __restrict__ w2,
    _Float16* __restrict__ outp, _Float16* __restrict__ W1p,
    _Float16* __restrict__ W2p) {
    int lx   = threadIdx.x;           // 0..63
    int nc   = threadIdx.y;           // 0..3
    int flat = nc*64 + lx;
    int tt = lx & 31, ch = lx >> 5;
    int Lb = blockIdx.x;
    int nh   = Lb & 1;                // n-half
    int t0   = ((Lb >> 1) & 15) << 5;
    int k    = (Lb >> 5) % 12;
    int b    = Lb / 384;

    // ---- weight repack (blocks 0..10 only; trivial extra work) ----
    if (Lb < 10) {
        for (int e = Lb*1152 + flat; e < Lb*1152 + 1152; e += 256) {
            int tap = e/1280, rem = e - tap*1280, co = rem/40, ci = rem - co*40;
            float val = (ci < 32) ? w2[(co*32+ci)*9 + tap] : 0.0f;
            W2p[e] = (_Float16)val;          // [tap][co][ci pad 40]
        }
    } else if (Lb == 10) {
        for (int e = flat; e < 32*40; e += 256) {
            int co = e/40, kk = e - co*40;
            float val = 0.0f;
            if (kk < 18) { int ci = kk & 1, tap = kk >> 1; val = w1[(co*2+ci)*9 + tap]; }
            W1p[e] = (_Float16)val;          // [co][k pad 40]
        }
    }

    // ---- lead constants (block-uniform; hoisted to SGPRs via rfl) ----
    float vx, vy, vz;
    if      (k == 0) { vx = la[0]-ra[0]; vy = la[1]-ra[1]; vz = la[2]-ra[2]; }
    else if (k == 1) { vx = ll[0]-ra[0]; vy = ll[1]-ra[1]; vz = ll[2]-ra[2]; }
    else if (k == 2) { vx = ll[0]-la[0]; vy = ll[1]-la[1]; vz = ll[2]-la[2]; }
    else if (k == 3) { vx = ra[0]-0.5f*(la[0]+ll[0]); vy = ra[1]-0.5f*(la[1]+ll[1]); vz = ra[2]-0.5f*(la[2]+ll[2]); }
    else if (k == 4) { vx = la[0]-0.5f*(ra[0]+ll[0]); vy = la[1]-0.5f*(ra[1]+ll[1]); vz = la[2]-0.5f*(ra[2]+ll[2]); }
    else if (k == 5) { vx = ll[0]-0.5f*(ra[0]+la[0]); vy = ll[1]-0.5f*(ra[1]+la[1]); vz = ll[2]-0.5f*(ra[2]+la[2]); }
    else             { vx = chest[(k-6)*3+0]; vy = chest[(k-6)*3+1]; vz = chest[(k-6)*3+2]; }
    float nn = fmaxf(sqrtf(vx*vx+vy*vy+vz*vz), 1e-6f);
    float Lx = vx/nn, Ly = vy/nn, Lz = vz/nn;
    // e1 = cross(L, x-axis) = (0, Lz, -Ly); if tiny, cross(L, y-axis) = (-Lz, 0, Lx)
    float e1x = 0.0f, e1y = Lz, e1z = -Ly;
    if (sqrtf(e1y*e1y + e1z*e1z) < 1e-4f) { e1x = -Lz; e1y = 0.0f; e1z = Lx; }
    float en = fmaxf(sqrtf(e1x*e1x+e1y*e1y+e1z*e1z), 1e-6f);
    e1x /= en; e1y /= en; e1z /= en;
    float e2x = e1y*Lz - e1z*Ly, e2y = e1z*Lx - e1x*Lz, e2z = e1x*Ly - e1y*Lx;
    float fn = fmaxf(sqrtf(e2x*e2x+e2y*e2y+e2z*e2z), 1e-6f);
    e2x /= fn; e2y /= fn; e2z /= fn;
    Lx = rfl(Lx); Ly = rfl(Ly); Lz = rfl(Lz);
    e1x = rfl(e1x); e1y = rfl(e1y); e1z = rfl(e1z);
    e2x = rfl(e2x); e2y = rfl(e2y); e2z = rfl(e2z);
    float Y[9];
    Y[0] = rfl( 0.282095f);
    Y[1] = rfl(-0.488603f*Ly);
    Y[2] = rfl( 0.488603f*Lz);
    Y[3] = rfl(-0.488603f*Lx);
    Y[4] = rfl( 1.092548f*Lx*Ly);
    Y[5] = rfl(-1.092548f*Ly*Lz);
    Y[6] = rfl( 0.315392f*fmaf(3.0f*Lz, Lz, -1.0f));
    Y[7] = rfl(-1.092548f*Lx*Lz);
    Y[8] = rfl( 0.546274f*(Lx*Lx - Ly*Ly));

    float tau = softplusf(tau_raw[0]) + 0.06f;
    float cc2 = rfl(0.5f/(tau*tau));
    float gamma = rfl(softplusf(da_raw[0]) + 1e-6f);
    const float S = 2.0f/7.0f;   // grid step of linspace(-1,1,8)
    float twoccS = rfl(2.0f*cc2*S);
    // ku[w] = exp(-c(u-g_w)^2) = exp(-c*du^2) * exp(2cS*du)^w * q[w],  du=u+1
    float q[8];
#pragma unroll
    for (int w = 0; w < 8; ++w) { float gw = S*(float)w; q[w] = rfl(__expf(-cc2*gw*gw)); }

    float tf = (float)(t0 + tt) * (1.0f/511.0f);
    floatx2 acc2[32];                 // [h][w/2] packed pairs (v_pk_fma_f32)
#pragma unroll
    for (int i = 0; i < 32; ++i) acc2[i] = (floatx2){0.f, 0.f};

    // ---- main loop: r0-proven body (global per-n loads, no LDS in chain) ----
    int n0 = nh*48 + nc*12;           // wave-uniform n
    for (int n = n0; n < n0+12; ++n) {
        int base = b*N_ + n;
        float dt  = tf - mu[base];
        float sig = softplus_small(fmaf(sgv[base], dt, sg0[base])) + 1e-3f;
        float z   = dt * __builtin_amdgcn_rcpf(sig);
        float gauss = amp[base] * __expf(-0.5f*z*z);
        float prx = fmaf(pv[base*3+0], dt, p0[base*3+0]);
        float pry = fmaf(pv[base*3+1], dt, p0[base*3+1]);
        float prz = fmaf(pv[base*3+2], dt, p0[base*3+2]);
        float nr  = sqrtf(prx*prx + pry*pry + prz*prz);
        float ncl = fmaxf(nr, 1e-8f);
        float th  = fast_tanhf(ncl);
        float scl = th * __builtin_amdgcn_rcpf(ncl);
        float px = prx*scl, py = pry*scl, pz = prz*scl;
        float pn = fmaxf(th, 1e-8f);            // == max(|p_pos|, 1e-8)
        float cosl = (px*Lx + py*Ly + pz*Lz) * __builtin_amdgcn_rcpf(pn);
        float hem  = fmaxf(cosl, 0.0f);
        if (gauss != 0.0f && hem > 0.0f) {
            // acos on [0,1): A-S 4.4.45 poly, abs err 6.7e-5
            float c = fminf(cosl, 0.999999f);
            float s = sqrtf(1.0f - c);
            float theta = s * fmaf(c, fmaf(c, fmaf(c, -0.0187293f, 0.0742610f),
                                   -0.2121144f), 1.5707288f);
            float A = gauss * hem * __expf(-gamma*theta*theta);
            // |dot(p_pos,e)| <= |p_pos| < 1 -> Pade tanh valid
            float uu = tanh_pade(px*e1x + py*e1y + pz*e1z);
            float vv = tanh_pade(px*e2x + py*e2y + pz*e2z);
            float Ach = A;
            if (ch) {                            // sh channel: lanes 32..63
                float shp = 0.0f;
#pragma unroll
                for (int m = 0; m < 9; ++m)
                    shp += fmaf(shv[base*9+m], dt, shb[base*9+m]) * Y[m];
                Ach = A * shp;
            }
            float du = uu + 1.0f, dv = vv + 1.0f;
            float bu = __expf(-cc2*du*du);
            float bv = __expf(-cc2*dv*dv);
            float ru = __expf(twoccS*du);
            float rv = __expf(twoccS*dv);
            floatx2 ku2[4];
            float rw = bu;
#pragma unroll
            for (int w = 0; w < 8; ++w) { ku2[w>>1][w&1] = rw*q[w]; rw *= ru; }
            rw = bv;
#pragma unroll
            for (int h = 0; h < 8; ++h) {
                float tp = (rw*q[h])*Ach; rw *= rv;
                floatx2 tp2 = (floatx2){tp, tp};
#pragma unroll
                for (int w2 = 0; w2 < 4; ++w2)
                    acc2[h*4+w2] = __builtin_elementwise_fma(tp2, ku2[w2], acc2[h*4+w2]);
            }
        }
    }
    // reduce the 4 n-chunks via LDS atomics (row stride 130 -> 2-way alias, free)
    __shared__ float red[32*130];
    for (int i = flat; i < 32*130; i += 256) red[i] = 0.0f;
    __syncthreads();
#pragma unroll
    for (int i = 0; i < 32; ++i) {
        atomicAdd(&red[tt*130 + ch*64 + 2*i],     acc2[i][0]);
        atomicAdd(&red[tt*130 + ch*64 + 2*i + 1], acc2[i][1]);
    }
    __syncthreads();
    // write PARTIAL 32 x 128 f16 into this n-half's buffer
    _Float16* po = outp + (size_t)nh * ((size_t)NIMG * 128);
    int imgbase = (b*12 + k)*T_ + t0;
    int e0 = flat*16, r = e0 >> 7, c0 = e0 & 127;
    half8 h0, h1;
#pragma unroll
    for (int j = 0; j < 8; ++j) {
        h0[j] = (_Float16)red[r*130 + c0 + j];
        h1[j] = (_Float16)red[r*130 + c0 + 8 + j];
    }
    *(half8*)&po[(imgbase + r)*128 + c0]     = h0;
    *(half8*)&po[(imgbase + r)*128 + c0 + 8] = h1;
}

// ---------- K2: CNN readout ----------
// 1 wave per image, 4 images per 256-thread block, grid = 6144.
// Input = sum of the two n-half partial splat buffers (r3-proven).
// IN stored channel-interleaved [10x10 pix][2 ci] so the conv1 A-gather is
// 16 x ds_read_b32 instead of 32 x ds_read_u16.
__global__ __launch_bounds__(256, 4) void cnn_kernel(
    const _Float16* __restrict__ splat, const _Float16* __restrict__ W1p,
    const _Float16* __restrict__ W2p,  const float* __restrict__ b1,
    const float* __restrict__ b2,      const float* __restrict__ fcw,
    const float* __restrict__ fcb,     float* __restrict__ outv) {
    __shared__ __align__(16) _Float16 sH1[4][100*40]; // per img: [10x10 padded pix][ch pad 40]
    __shared__ __align__(16) _Float16 sIn[4][200];    // per img: [10x10 padded pix][2 ci]
    int tid = threadIdx.x;
    int wv = tid >> 6, lane = tid & 63;
    int img = blockIdx.x*4 + wv;
    _Float16* H  = sH1[wv];
    _Float16* IN = sIn[wv];
    {   // zero halo regions (wave-private)
        unsigned long long* hz = (unsigned long long*)H;
        for (int i = lane; i < 1000; i += 64) hz[i] = 0ull;
        unsigned int* iz = (unsigned int*)IN;
        for (int i = lane; i < 100; i += 64) iz[i] = 0u;
    }
    // stage input 2x8x8 into padded [10x10][2] (sum the two n-half partials)
#pragma unroll
    for (int ii = 0; ii < 2; ++ii) {
        int i = ii*64 + lane;
        int ci = i >> 6, p = i & 63;
        float v = (float)splat[img*128 + i]
                + (float)splat[(size_t)NIMG*128 + img*128 + i];
        IN[(((p>>3)+1)*10 + (p&7) + 1)*2 + ci] = (_Float16)v;
    }
    __syncthreads();

    int r = lane & 15, qd = lane >> 4;
    // ---- conv1: M=64 pix, N=32 ch, K=18 (pad 32) ----
    floatx4 c1[2][4];
#pragma unroll
    for (int nt = 0; nt < 2; ++nt)
#pragma unroll
      for (int mt = 0; mt < 4; ++mt) c1[nt][mt] = (floatx4){0.f,0.f,0.f,0.f};
    half8 bw[2];
#pragma unroll
    for (int nt = 0; nt < 2; ++nt)
        bw[nt] = *(const half8*)&W1p[(nt*16+r)*40 + qd*8];
#pragma unroll
    for (int mt = 0; mt < 4; ++mt) {
        int p = mt*16 + r, py = p>>3, px = p&7;
        half8 a;
#pragma unroll
        for (int m = 0; m < 4; ++m) {
            int tap = qd*4 + m;                    // kk = 2*tap + ci
            int tc  = (tap > 8) ? 8 : tap;         // clamp keeps address in-bounds
            int ky = tc/3, kx = tc - ky*3;
            half2t pr = *(const half2t*)&IN[((py+ky)*10 + (px+kx))*2];
            if (tap >= 9) { pr[0] = (_Float16)0.0f; pr[1] = (_Float16)0.0f; }
            a[2*m]   = pr[0];
            a[2*m+1] = pr[1];
        }
#pragma unroll
        for (int nt = 0; nt < 2; ++nt)
            c1[nt][mt] = __builtin_amdgcn_mfma_f32_16x16x32_f16(a, bw[nt], c1[nt][mt], 0, 0, 0);
    }
    // bias + gelu -> H (padded [pix][ch])
    float bias1[2] = { b1[r], b1[16+r] };
#pragma unroll
    for (int nt = 0; nt < 2; ++nt)
#pragma unroll
      for (int mt = 0; mt < 4; ++mt)
#pragma unroll
        for (int j = 0; j < 4; ++j) {
            int p = mt*16 + qd*4 + j, py = p>>3, px = p&7;
            float g = geluf(c1[nt][mt][j] + bias1[nt]);
            H[((py+1)*10 + (px+1))*40 + nt*16 + r] = (_Float16)g;
        }
    __syncthreads();
    // ---- conv2: M=64, N=32, K=288 (9 taps x 32 ch) ----
    floatx4 c2[2][4];
#pragma unroll
    for (int nt = 0; nt < 2; ++nt)
#pragma unroll
      for (int mt = 0; mt < 4; ++mt) c2[nt][mt] = (floatx4){0.f,0.f,0.f,0.f};
#pragma unroll
    for (int tap = 0; tap < 9; ++tap) {
        int ky = tap/3, kx = tap - (tap/3)*3;
        half8 wb[2];
#pragma unroll
        for (int nt = 0; nt < 2; ++nt)
            wb[nt] = *(const half8*)&W2p[tap*1280 + (nt*16+r)*40 + qd*8];
#pragma unroll
        for (int mt = 0; mt < 4; ++mt) {
            int p = mt*16 + r, py = p>>3, px = p&7;
            half8 a = *(const half8*)&H[((py+ky)*10 + (px+kx))*40 + qd*8];
#pragma unroll
            for (int nt = 0; nt < 2; ++nt)
                c2[nt][mt] = __builtin_amdgcn_mfma_f32_16x16x32_f16(a, wb[nt], c2[nt][mt], 0, 0, 0);
        }
    }
    // bias + gelu + mean-pool + fc
    float bias2[2] = { b2[r], b2[16+r] };
    float chs0 = 0.f, chs1 = 0.f;
#pragma unroll
    for (int mt = 0; mt < 4; ++mt)
#pragma unroll
      for (int j = 0; j < 4; ++j) {
        chs0 += geluf(c2[0][mt][j] + bias2[0]);
        chs1 += geluf(c2[1][mt][j] + bias2[1]);
      }
    chs0 += __shfl_xor(chs0, 16); chs0 += __shfl_xor(chs0, 32);
    chs1 += __shfl_xor(chs1, 16); chs1 += __shfl_xor(chs1, 32);
    float tot = (chs0 * fcw[r] + chs1 * fcw[16+r]) * (1.0f/64.0f);
    tot += __shfl_xor(tot, 1); tot += __shfl_xor(tot, 2);
    tot += __shfl_xor(tot, 4); tot += __shfl_xor(tot, 8);
    tot += fcb[0];
    if (lane == 0) {
        int t = img & 511, bk = img >> 9;
        int kk = bk % 12, bb = bk / 12;
        // faithful torch permutation: out[b, :, :].flat = scalars[b].T.flat
        outv[(bb*T_ + t)*12 + kk] = tot;
    }
}

extern "C" void kernel_launch(void* const* d_in, const int* in_sizes, int n_in,
                              void* d_out, int out_size, void* d_ws, size_t ws_size,
                              hipStream_t stream) {
    const float* mu   = (const float*)d_in[0];
    const float* sg0  = (const float*)d_in[1];
    const float* sgv  = (const float*)d_in[2];
    const float* amp  = (const float*)d_in[3];
    const float* shb  = (const float*)d_in[4];
    const float* shv  = (const float*)d_in[5];
    const float* p0   = (const float*)d_in[6];
    const float* pvel = (const float*)d_in[7];
    const float* taur = (const float*)d_in[8];
    const float* dar  = (const float*)d_in[9];
    const float* ra   = (const float*)d_in[10];
    const float* la   = (const float*)d_in[11];
    const float* ll   = (const float*)d_in[12];
    const float* chest= (const float*)d_in[13];
    const float* w1   = (const float*)d_in[14];
    const float* b1   = (const float*)d_in[15];
    const float* w2   = (const float*)d_in[16];
    const float* b2   = (const float*)d_in[17];
    const float* fcw  = (const float*)d_in[18];
    const float* fcb  = (const float*)d_in[19];

    char* ws = (char*)d_ws;
    _Float16*  W1p   = (_Float16*)ws;            // 2560 B
    _Float16*  W2p   = (_Float16*)(ws + 4096);   // 23040 B
    _Float16*  splat = (_Float16*)(ws + 32768);  // 2 x 6.29 MB partial buffers

    splat_kernel<<<1536, dim3(64,4), 0, stream>>>(mu, sg0, sgv, amp, shb, shv, p0, pvel,
                                                  taur, dar, ra, la, ll, chest, w1, w2,
                                                  splat, W1p, W2p);
    cnn_kernel<<<NIMG/4, 256, 0, stream>>>(splat, W1p, W2p, b1, b2, fcw, fcb, (float*)d_out);
}

// Round 6
// 192.194 us; speedup vs baseline: 1.5702x; 1.5702x over previous
//
#include <hip/hip_runtime.h>

// Problem constants (fixed by reference setup)
#define B_ 4
#define N_ 96
#define T_ 512
#define G_ 8
#define NIMG (B_*12*T_)   // 24576 images

typedef _Float16 half8 __attribute__((ext_vector_type(8)));
typedef _Float16 half2t __attribute__((ext_vector_type(2)));
typedef float floatx4 __attribute__((ext_vector_type(4)));
typedef float floatx2 __attribute__((ext_vector_type(2)));

// ---------- math helpers ----------
__device__ __forceinline__ float softplusf(float x) {
    return (x > 15.0f) ? x : __logf(1.0f + __expf(x));
}
// branchless softplus (sigma path: args within +-4)
__device__ __forceinline__ float softplus_small(float x) {
    return __logf(1.0f + __expf(x));
}
__device__ __forceinline__ float fast_tanhf(float x) {
    float ax = fabsf(x);
    float e  = __expf(-2.0f * ax);
    float r  = (1.0f - e) * __builtin_amdgcn_rcpf(1.0f + e);
    return copysignf(r, x);
}
// odd Pade(5,4) tanh, |x| <= 1: abs err ~1e-5, no exp (r3/r4/r5-verified)
__device__ __forceinline__ float tanh_pade(float x) {
    float x2 = x * x;
    float num = fmaf(x2, x2 + 105.0f, 945.0f);          // x^4+105x^2+945
    float den = fmaf(x2, fmaf(x2, 15.0f, 420.0f), 945.0f);
    return x * num * __builtin_amdgcn_rcpf(den);
}
// GELU with 3-term Abramowitz-Stegun erf (abs err 2.5e-5)
__device__ __forceinline__ float geluf(float x) {
    float z  = 0.70710678118654752f * x;
    float az = fabsf(z);
    float t  = __builtin_amdgcn_rcpf(fmaf(0.47047f, az, 1.0f));
    float poly = t * fmaf(t, fmaf(t, 0.7478556f, -0.0958798f), 0.3480242f);
    float e  = __expf(-az * az);
    float er = fmaf(-poly, e, 1.0f);     // erf(|z|)
    er = copysignf(er, z);
    return 0.5f * x * (1.0f + er);
}
// force a block-uniform float into an SGPR
__device__ __forceinline__ float rfl(float x) {
    return __int_as_float(__builtin_amdgcn_readfirstlane(__float_as_int(x)));
}

// ---------- K1: splat ----------
// grid 768 = (b, k, 16 t-tiles of 32). block (64,4): r0-proven layout —
// wave = 32t x 2ch (n wave-uniform), threadIdx.y = n-chunk (24 n each).
// r0-r5 ledger model: wall = W_loop(~30us) + blocks/CU x E_epilogue, and
// E was ~19us/block when the reduce used 16384 LDS f32 atomicAdds/block
// (4 lanes/bank RMW). This version replaces atomics with 4 barrier-ordered
// wave passes of plain ds_read_b128/ds_write_b128 (pass 0 writes, so no
// zero-init). Row stride 132 words keeps every 16B access aligned and
// bank-spread. Expected E ~1us/block.
__global__ __launch_bounds__(256, 3) void splat_kernel(
    const float* __restrict__ mu,  const float* __restrict__ sg0,
    const float* __restrict__ sgv, const float* __restrict__ amp,
    const float* __restrict__ shb, const float* __restrict__ shv,
    const float* __restrict__ p0,  const float* __restrict__ pv,
    const float* __restrict__ tau_raw, const float* __restrict__ da_raw,
    const float* __restrict__ ra, const float* __restrict__ la,
    const float* __restrict__ ll, const float* __restrict__ chest,
    const float* __restrict__ w1, const float* __restrict__ w2,
    _Float16* __restrict__ outp, _Float16* __restrict__ W1p,
    _Float16* __restrict__ W2p) {
    int lx   = threadIdx.x;           // 0..63
    int nc   = threadIdx.y;           // 0..3
    int flat = nc*64 + lx;
    int tt = lx & 31, ch = lx >> 5;
    int Lb = blockIdx.x;
    int t0 = (Lb & 15) << 5;
    int k  = (Lb >> 4) % 12;
    int b  = Lb / 192;

    // ---- weight repack (blocks 0..10 only; trivial extra work) ----
    if (Lb < 10) {
        for (int e = Lb*1152 + flat; e < Lb*1152 + 1152; e += 256) {
            int tap = e/1280, rem = e - tap*1280, co = rem/40, ci = rem - co*40;
            float val = (ci < 32) ? w2[(co*32+ci)*9 + tap] : 0.0f;
            W2p[e] = (_Float16)val;          // [tap][co][ci pad 40]
        }
    } else if (Lb == 10) {
        for (int e = flat; e < 32*40; e += 256) {
            int co = e/40, kk = e - co*40;
            float val = 0.0f;
            if (kk < 18) { int ci = kk & 1, tap = kk >> 1; val = w1[(co*2+ci)*9 + tap]; }
            W1p[e] = (_Float16)val;          // [co][k pad 40]
        }
    }

    // ---- lead constants (block-uniform; hoisted to SGPRs via rfl) ----
    float vx, vy, vz;
    if      (k == 0) { vx = la[0]-ra[0]; vy = la[1]-ra[1]; vz = la[2]-ra[2]; }
    else if (k == 1) { vx = ll[0]-ra[0]; vy = ll[1]-ra[1]; vz = ll[2]-ra[2]; }
    else if (k == 2) { vx = ll[0]-la[0]; vy = ll[1]-la[1]; vz = ll[2]-la[2]; }
    else if (k == 3) { vx = ra[0]-0.5f*(la[0]+ll[0]); vy = ra[1]-0.5f*(la[1]+ll[1]); vz = ra[2]-0.5f*(la[2]+ll[2]); }
    else if (k == 4) { vx = la[0]-0.5f*(ra[0]+ll[0]); vy = la[1]-0.5f*(ra[1]+ll[1]); vz = la[2]-0.5f*(ra[2]+ll[2]); }
    else if (k == 5) { vx = ll[0]-0.5f*(ra[0]+la[0]); vy = ll[1]-0.5f*(ra[1]+la[1]); vz = ll[2]-0.5f*(ra[2]+la[2]); }
    else             { vx = chest[(k-6)*3+0]; vy = chest[(k-6)*3+1]; vz = chest[(k-6)*3+2]; }
    float nn = fmaxf(sqrtf(vx*vx+vy*vy+vz*vz), 1e-6f);
    float Lx = vx/nn, Ly = vy/nn, Lz = vz/nn;
    // e1 = cross(L, x-axis) = (0, Lz, -Ly); if tiny, cross(L, y-axis) = (-Lz, 0, Lx)
    float e1x = 0.0f, e1y = Lz, e1z = -Ly;
    if (sqrtf(e1y*e1y + e1z*e1z) < 1e-4f) { e1x = -Lz; e1y = 0.0f; e1z = Lx; }
    float en = fmaxf(sqrtf(e1x*e1x+e1y*e1y+e1z*e1z), 1e-6f);
    e1x /= en; e1y /= en; e1z /= en;
    float e2x = e1y*Lz - e1z*Ly, e2y = e1z*Lx - e1x*Lz, e2z = e1x*Ly - e1y*Lx;
    float fn = fmaxf(sqrtf(e2x*e2x+e2y*e2y+e2z*e2z), 1e-6f);
    e2x /= fn; e2y /= fn; e2z /= fn;
    Lx = rfl(Lx); Ly = rfl(Ly); Lz = rfl(Lz);
    e1x = rfl(e1x); e1y = rfl(e1y); e1z = rfl(e1z);
    e2x = rfl(e2x); e2y = rfl(e2y); e2z = rfl(e2z);
    float Y[9];
    Y[0] = rfl( 0.282095f);
    Y[1] = rfl(-0.488603f*Ly);
    Y[2] = rfl( 0.488603f*Lz);
    Y[3] = rfl(-0.488603f*Lx);
    Y[4] = rfl( 1.092548f*Lx*Ly);
    Y[5] = rfl(-1.092548f*Ly*Lz);
    Y[6] = rfl( 0.315392f*fmaf(3.0f*Lz, Lz, -1.0f));
    Y[7] = rfl(-1.092548f*Lx*Lz);
    Y[8] = rfl( 0.546274f*(Lx*Lx - Ly*Ly));

    float tau = softplusf(tau_raw[0]) + 0.06f;
    float cc2 = rfl(0.5f/(tau*tau));
    float gamma = rfl(softplusf(da_raw[0]) + 1e-6f);
    const float S = 2.0f/7.0f;   // grid step of linspace(-1,1,8)
    float twoccS = rfl(2.0f*cc2*S);
    // ku[w] = exp(-c(u-g_w)^2) = exp(-c*du^2) * exp(2cS*du)^w * q[w],  du=u+1
    float q[8];
#pragma unroll
    for (int w = 0; w < 8; ++w) { float gw = S*(float)w; q[w] = rfl(__expf(-cc2*gw*gw)); }

    float tf = (float)(t0 + tt) * (1.0f/511.0f);
    floatx2 acc2[32];                 // [h][w/2] packed pairs (v_pk_fma_f32)
#pragma unroll
    for (int i = 0; i < 32; ++i) acc2[i] = (floatx2){0.f, 0.f};

    // ---- main loop: r0-proven body (global per-n loads, no LDS in chain) ----
    int n0 = nc*24;
    for (int n = n0; n < n0+24; ++n) {
        int base = b*N_ + n;
        float dt  = tf - mu[base];
        float sig = softplus_small(fmaf(sgv[base], dt, sg0[base])) + 1e-3f;
        float z   = dt * __builtin_amdgcn_rcpf(sig);
        float gauss = amp[base] * __expf(-0.5f*z*z);
        float prx = fmaf(pv[base*3+0], dt, p0[base*3+0]);
        float pry = fmaf(pv[base*3+1], dt, p0[base*3+1]);
        float prz = fmaf(pv[base*3+2], dt, p0[base*3+2]);
        float nr  = sqrtf(prx*prx + pry*pry + prz*prz);
        float ncl = fmaxf(nr, 1e-8f);
        float th  = fast_tanhf(ncl);
        float scl = th * __builtin_amdgcn_rcpf(ncl);
        float px = prx*scl, py = pry*scl, pz = prz*scl;
        float pn = fmaxf(th, 1e-8f);            // == max(|p_pos|, 1e-8)
        float cosl = (px*Lx + py*Ly + pz*Lz) * __builtin_amdgcn_rcpf(pn);
        float hem  = fmaxf(cosl, 0.0f);
        if (gauss != 0.0f && hem > 0.0f) {
            // acos on [0,1): A-S 4.4.45 poly, abs err 6.7e-5
            float c = fminf(cosl, 0.999999f);
            float s = sqrtf(1.0f - c);
            float theta = s * fmaf(c, fmaf(c, fmaf(c, -0.0187293f, 0.0742610f),
                                   -0.2121144f), 1.5707288f);
            float A = gauss * hem * __expf(-gamma*theta*theta);
            // |dot(p_pos,e)| <= |p_pos| < 1 -> Pade tanh valid
            float uu = tanh_pade(px*e1x + py*e1y + pz*e1z);
            float vv = tanh_pade(px*e2x + py*e2y + pz*e2z);
            float Ach = A;
            if (ch) {                            // sh channel: lanes 32..63
                float shp = 0.0f;
#pragma unroll
                for (int m = 0; m < 9; ++m)
                    shp += fmaf(shv[base*9+m], dt, shb[base*9+m]) * Y[m];
                Ach = A * shp;
            }
            float du = uu + 1.0f, dv = vv + 1.0f;
            float bu = __expf(-cc2*du*du);
            float bv = __expf(-cc2*dv*dv);
            float ru = __expf(twoccS*du);
            float rv = __expf(twoccS*dv);
            floatx2 ku2[4];
            float rw = bu;
#pragma unroll
            for (int w = 0; w < 8; ++w) { ku2[w>>1][w&1] = rw*q[w]; rw *= ru; }
            rw = bv;
#pragma unroll
            for (int h = 0; h < 8; ++h) {
                float tp = (rw*q[h])*Ach; rw *= rv;
                floatx2 tp2 = (floatx2){tp, tp};
#pragma unroll
                for (int w2 = 0; w2 < 4; ++w2)
                    acc2[h*4+w2] = __builtin_elementwise_fma(tp2, ku2[w2], acc2[h*4+w2]);
            }
        }
    }

    // ---- reduce: 4 barrier-ordered wave passes, plain b128 LDS ops ----
    // red[32][132]: stride 132 words -> every (tt*132 + ch*64 + 4j) offset is
    // 16B-aligned (132*4 = 528 = 33*16); pass 0 writes (no zero-init needed).
    __shared__ float red[32*132];
    int rbase = tt*132 + ch*64;
    if (nc == 0) {
#pragma unroll
        for (int j = 0; j < 16; ++j) {
            floatx4 v = { acc2[2*j][0], acc2[2*j][1], acc2[2*j+1][0], acc2[2*j+1][1] };
            *(floatx4*)&red[rbase + 4*j] = v;
        }
    }
    __syncthreads();
    if (nc == 1) {
#pragma unroll
        for (int j = 0; j < 16; ++j) {
            floatx4 cur = *(const floatx4*)&red[rbase + 4*j];
            cur[0] += acc2[2*j][0]; cur[1] += acc2[2*j][1];
            cur[2] += acc2[2*j+1][0]; cur[3] += acc2[2*j+1][1];
            *(floatx4*)&red[rbase + 4*j] = cur;
        }
    }
    __syncthreads();
    if (nc == 2) {
#pragma unroll
        for (int j = 0; j < 16; ++j) {
            floatx4 cur = *(const floatx4*)&red[rbase + 4*j];
            cur[0] += acc2[2*j][0]; cur[1] += acc2[2*j][1];
            cur[2] += acc2[2*j+1][0]; cur[3] += acc2[2*j+1][1];
            *(floatx4*)&red[rbase + 4*j] = cur;
        }
    }
    __syncthreads();
    if (nc == 3) {
#pragma unroll
        for (int j = 0; j < 16; ++j) {
            floatx4 cur = *(const floatx4*)&red[rbase + 4*j];
            cur[0] += acc2[2*j][0]; cur[1] += acc2[2*j][1];
            cur[2] += acc2[2*j+1][0]; cur[3] += acc2[2*j+1][1];
            *(floatx4*)&red[rbase + 4*j] = cur;
        }
    }
    __syncthreads();

    // write out 32 x 128 f16, 16 consecutive per thread (two 16B stores)
    int imgbase = (b*12 + k)*T_ + t0;
    int e0 = flat*16, r = e0 >> 7, c0 = e0 & 127;
    half8 h0, h1;
#pragma unroll
    for (int j = 0; j < 8; ++j) {
        h0[j] = (_Float16)red[r*132 + c0 + j];
        h1[j] = (_Float16)red[r*132 + c0 + 8 + j];
    }
    *(half8*)&outp[(imgbase + r)*128 + c0]     = h0;
    *(half8*)&outp[(imgbase + r)*128 + c0 + 8] = h1;
}

// ---------- K2: CNN readout ----------
// 1 wave per image, 4 images per 256-thread block, grid = 6144.
// IN stored channel-interleaved [10x10 pix][2 ci] so the conv1 A-gather is
// 16 x ds_read_b32 instead of 32 x ds_read_u16 (r5-verified).
__global__ __launch_bounds__(256, 4) void cnn_kernel(
    const _Float16* __restrict__ splat, const _Float16* __restrict__ W1p,
    const _Float16* __restrict__ W2p,  const float* __restrict__ b1,
    const float* __restrict__ b2,      const float* __restrict__ fcw,
    const float* __restrict__ fcb,     float* __restrict__ outv) {
    __shared__ __align__(16) _Float16 sH1[4][100*40]; // per img: [10x10 padded pix][ch pad 40]
    __shared__ __align__(16) _Float16 sIn[4][200];    // per img: [10x10 padded pix][2 ci]
    int tid = threadIdx.x;
    int wv = tid >> 6, lane = tid & 63;
    int img = blockIdx.x*4 + wv;
    _Float16* H  = sH1[wv];
    _Float16* IN = sIn[wv];
    {   // zero halo regions (wave-private)
        unsigned long long* hz = (unsigned long long*)H;
        for (int i = lane; i < 1000; i += 64) hz[i] = 0ull;
        unsigned int* iz = (unsigned int*)IN;
        for (int i = lane; i < 100; i += 64) iz[i] = 0u;
    }
    // stage input 2x8x8 into padded [10x10][2]
#pragma unroll
    for (int ii = 0; ii < 2; ++ii) {
        int i = ii*64 + lane;
        int ci = i >> 6, p = i & 63;
        IN[(((p>>3)+1)*10 + (p&7) + 1)*2 + ci] = splat[img*128 + i];
    }
    __syncthreads();

    int r = lane & 15, qd = lane >> 4;
    // ---- conv1: M=64 pix, N=32 ch, K=18 (pad 32) ----
    floatx4 c1[2][4];
#pragma unroll
    for (int nt = 0; nt < 2; ++nt)
#pragma unroll
      for (int mt = 0; mt < 4; ++mt) c1[nt][mt] = (floatx4){0.f,0.f,0.f,0.f};
    half8 bw[2];
#pragma unroll
    for (int nt = 0; nt < 2; ++nt)
        bw[nt] = *(const half8*)&W1p[(nt*16+r)*40 + qd*8];
#pragma unroll
    for (int mt = 0; mt < 4; ++mt) {
        int p = mt*16 + r, py = p>>3, px = p&7;
        half8 a;
#pragma unroll
        for (int m = 0; m < 4; ++m) {
            int tap = qd*4 + m;                    // kk = 2*tap + ci
            int tc  = (tap > 8) ? 8 : tap;         // clamp keeps address in-bounds
            int ky = tc/3, kx = tc - ky*3;
            half2t pr = *(const half2t*)&IN[((py+ky)*10 + (px+kx))*2];
            if (tap >= 9) { pr[0] = (_Float16)0.0f; pr[1] = (_Float16)0.0f; }
            a[2*m]   = pr[0];
            a[2*m+1] = pr[1];
        }
#pragma unroll
        for (int nt = 0; nt < 2; ++nt)
            c1[nt][mt] = __builtin_amdgcn_mfma_f32_16x16x32_f16(a, bw[nt], c1[nt][mt], 0, 0, 0);
    }
    // bias + gelu -> H (padded [pix][ch])
    float bias1[2] = { b1[r], b1[16+r] };
#pragma unroll
    for (int nt = 0; nt < 2; ++nt)
#pragma unroll
      for (int mt = 0; mt < 4; ++mt)
#pragma unroll
        for (int j = 0; j < 4; ++j) {
            int p = mt*16 + qd*4 + j, py = p>>3, px = p&7;
            float g = geluf(c1[nt][mt][j] + bias1[nt]);
            H[((py+1)*10 + (px+1))*40 + nt*16 + r] = (_Float16)g;
        }
    __syncthreads();
    // ---- conv2: M=64, N=32, K=288 (9 taps x 32 ch) ----
    floatx4 c2[2][4];
#pragma unroll
    for (int nt = 0; nt < 2; ++nt)
#pragma unroll
      for (int mt = 0; mt < 4; ++mt) c2[nt][mt] = (floatx4){0.f,0.f,0.f,0.f};
#pragma unroll
    for (int tap = 0; tap < 9; ++tap) {
        int ky = tap/3, kx = tap - (tap/3)*3;
        half8 wb[2];
#pragma unroll
        for (int nt = 0; nt < 2; ++nt)
            wb[nt] = *(const half8*)&W2p[tap*1280 + (nt*16+r)*40 + qd*8];
#pragma unroll
        for (int mt = 0; mt < 4; ++mt) {
            int p = mt*16 + r, py = p>>3, px = p&7;
            half8 a = *(const half8*)&H[((py+ky)*10 + (px+kx))*40 + qd*8];
#pragma unroll
            for (int nt = 0; nt < 2; ++nt)
                c2[nt][mt] = __builtin_amdgcn_mfma_f32_16x16x32_f16(a, wb[nt], c2[nt][mt], 0, 0, 0);
        }
    }
    // bias + gelu + mean-pool + fc
    float bias2[2] = { b2[r], b2[16+r] };
    float chs0 = 0.f, chs1 = 0.f;
#pragma unroll
    for (int mt = 0; mt < 4; ++mt)
#pragma unroll
      for (int j = 0; j < 4; ++j) {
        chs0 += geluf(c2[0][mt][j] + bias2[0]);
        chs1 += geluf(c2[1][mt][j] + bias2[1]);
      }
    chs0 += __shfl_xor(chs0, 16); chs0 += __shfl_xor(chs0, 32);
    chs1 += __shfl_xor(chs1, 16); chs1 += __shfl_xor(chs1, 32);
    float tot = (chs0 * fcw[r] + chs1 * fcw[16+r]) * (1.0f/64.0f);
    tot += __shfl_xor(tot, 1); tot += __shfl_xor(tot, 2);
    tot += __shfl_xor(tot, 4); tot += __shfl_xor(tot, 8);
    tot += fcb[0];
    if (lane == 0) {
        int t = img & 511, bk = img >> 9;
        int kk = bk % 12, bb = bk / 12;
        // faithful torch permutation: out[b, :, :].flat = scalars[b].T.flat
        outv[(bb*T_ + t)*12 + kk] = tot;
    }
}

extern "C" void kernel_launch(void* const* d_in, const int* in_sizes, int n_in,
                              void* d_out, int out_size, void* d_ws, size_t ws_size,
                              hipStream_t stream) {
    const float* mu   = (const float*)d_in[0];
    const float* sg0  = (const float*)d_in[1];
    const float* sgv  = (const float*)d_in[2];
    const float* amp  = (const float*)d_in[3];
    const float* shb  = (const float*)d_in[4];
    const float* shv  = (const float*)d_in[5];
    const float* p0   = (const float*)d_in[6];
    const float* pvel = (const float*)d_in[7];
    const float* taur = (const float*)d_in[8];
    const float* dar  = (const float*)d_in[9];
    const float* ra   = (const float*)d_in[10];
    const float* la   = (const float*)d_in[11];
    const float* ll   = (const float*)d_in[12];
    const float* chest= (const float*)d_in[13];
    const float* w1   = (const float*)d_in[14];
    const float* b1   = (const float*)d_in[15];
    const float* w2   = (const float*)d_in[16];
    const float* b2   = (const float*)d_in[17];
    const float* fcw  = (const float*)d_in[18];
    const float* fcb  = (const float*)d_in[19];

    char* ws = (char*)d_ws;
    _Float16*  W1p   = (_Float16*)ws;            // 2560 B
    _Float16*  W2p   = (_Float16*)(ws + 4096);   // 23040 B
    _Float16*  splat = (_Float16*)(ws + 32768);  // 6.29 MB

    splat_kernel<<<768, dim3(64,4), 0, stream>>>(mu, sg0, sgv, amp, shb, shv, p0, pvel,
                                                 taur, dar, ra, la, ll, chest, w1, w2,
                                                 splat, W1p, W2p);
    cnn_kernel<<<NIMG/4, 256, 0, stream>>>(splat, W1p, W2p, b1, b2, fcw, fcb, (float*)d_out);
}